// Round 8
// baseline (278.114 us; speedup 1.0000x reference)
//
#include <hip/hip_runtime.h>

#define NN 50000
#define NE 800000

typedef __attribute__((ext_vector_type(8))) short short8;
typedef __attribute__((ext_vector_type(4))) float f32x4;

#define SCAN_NB ((NN + 1023) / 1024)  // 49 blocks

// ---------------- bf16 helpers (RNE) ----------------
__device__ __forceinline__ unsigned short f2bf(float f) {
  union { float f; unsigned u; } v; v.f = f;
  unsigned r = (v.u + 0x7FFFu + ((v.u >> 16) & 1u)) >> 16;
  return (unsigned short)r;
}
__device__ __forceinline__ float bflo(unsigned u) {
  union { unsigned x; float f; } v; v.x = u << 16; return v.f;
}
__device__ __forceinline__ float bfhi(unsigned u) {
  union { unsigned x; float f; } v; v.x = u & 0xFFFF0000u; return v.f;
}

// ---------------- threefry2x32, JAX partitionable, key = (0, 42) ----------------
__device__ __forceinline__ unsigned tf_rotl(unsigned x, int r) {
#if __has_builtin(__builtin_amdgcn_alignbit)
  return __builtin_amdgcn_alignbit(x, x, 32 - r);
#else
  return (x << r) | (x >> (32 - r));
#endif
}
__device__ __forceinline__ void threefry_0_42(unsigned x0, unsigned x1,
                                              unsigned& o0, unsigned& o1) {
  const unsigned k0 = 0u, k1 = 42u;
  const unsigned k2 = k0 ^ k1 ^ 0x1BD11BDAu;
  x0 += k0; x1 += k1;
#define TF_R(r) { x0 += x1; x1 = tf_rotl(x1, (r)); x1 ^= x0; }
  TF_R(13) TF_R(15) TF_R(26) TF_R(6)
  x0 += k1; x1 += k2 + 1u;
  TF_R(17) TF_R(29) TF_R(16) TF_R(24)
  x0 += k2; x1 += k0 + 2u;
  TF_R(13) TF_R(15) TF_R(26) TF_R(6)
  x0 += k0; x1 += k1 + 3u;
  TF_R(17) TF_R(29) TF_R(16) TF_R(24)
  x0 += k1; x1 += k2 + 4u;
  TF_R(13) TF_R(15) TF_R(26) TF_R(6)
  x0 += k2; x1 += k0 + 5u;
#undef TF_R
  o0 = x0; o1 = x1;
}
__device__ __forceinline__ unsigned char drop_keep(unsigned flat) {
  unsigned o0, o1;
  threefry_0_42(0u, flat, o0, o1);
  unsigned bits = o0 ^ o1;
  float u = __uint_as_float((bits >> 9) | 0x3f800000u) - 1.0f;
  return (u < 0.9f) ? 1 : 0;
}

// dedicated full-occupancy mask kernel: 12.8M u8 keep-flags
__global__ __launch_bounds__(256) void mask_k(uchar4* __restrict__ m) {
  int i = blockIdx.x * 256 + threadIdx.x;  // 3.2M
  if (i >= NN * 256 / 4) return;
  unsigned base = (unsigned)i * 4u;
  uchar4 r;
  r.x = drop_keep(base + 0);
  r.y = drop_keep(base + 1);
  r.z = drop_keep(base + 2);
  r.w = drop_keep(base + 3);
  m[i] = r;
}

// ---------------- prep: conversions / weight packing ----------------
__global__ void cvtx_k(const float4* __restrict__ x, uint2* __restrict__ xb, int n4) {
  int i = blockIdx.x * 256 + threadIdx.x;
  if (i >= n4) return;
  float4 v = x[i];
  uint2 o;
  o.x = (unsigned)f2bf(v.x) | ((unsigned)f2bf(v.y) << 16);
  o.y = (unsigned)f2bf(v.z) | ((unsigned)f2bf(v.w) << 16);
  xb[i] = o;
}

// combined weight packer: idx<65536 -> W1t, else W2t
// W1t[n][k]: k<128 -> Wr1[k][n], else Wl1[k-128][n]
// W2t[n][k]: n<128 -> Wl2[k][n], else Wr2[k][n-128]
__global__ void mkw_k(const float* __restrict__ Wl1, const float* __restrict__ Wr1,
                      const float* __restrict__ Wl2, const float* __restrict__ Wr2,
                      unsigned short* __restrict__ W1t, unsigned short* __restrict__ W2t) {
  int gid = blockIdx.x * 256 + threadIdx.x;  // 131072
  int idx = gid & 65535;
  int n = idx >> 8, k = idx & 255;
  if (gid < 65536) {
    float v = (k < 128) ? Wr1[(size_t)k * 256 + n] : Wl1[(size_t)(k - 128) * 256 + n];
    W1t[idx] = f2bf(v);
  } else {
    float v = (n < 128) ? Wl2[(size_t)k * 128 + n] : Wr2[(size_t)k * 128 + (n - 128)];
    W2t[idx] = f2bf(v);
  }
}

// ---------------- CSR build ----------------
__global__ void zero4_k(float4* p, int n4) {
  int i = blockIdx.x * blockDim.x + threadIdx.x;
  if (i < n4) p[i] = make_float4(0.f, 0.f, 0.f, 0.f);
}

__global__ void count_k(const int* __restrict__ dst, unsigned* __restrict__ cnt) {
  int e = blockIdx.x * blockDim.x + threadIdx.x;
  if (e < NE) {
    unsigned d = (unsigned)dst[e];
    if (d < (unsigned)NN) atomicAdd(&cnt[d], 1u);
  }
}

__global__ void inv_k(const unsigned* __restrict__ cnt, float* __restrict__ inv) {
  int n = blockIdx.x * blockDim.x + threadIdx.x;
  if (n < NN) inv[n] = 1.0f / fmaxf((float)cnt[n], 1.0f);
}

// two-level scan: A) block-local exclusive scan + block sums
__global__ __launch_bounds__(1024) void scanA_k(const unsigned* __restrict__ cnt,
                                                unsigned* __restrict__ rowptr,
                                                unsigned* __restrict__ bsum) {
  __shared__ unsigned s[1024];
  int i = blockIdx.x * 1024 + threadIdx.x;
  unsigned v = (i < NN) ? cnt[i] : 0u;
  s[threadIdx.x] = v;
  __syncthreads();
  for (int off = 1; off < 1024; off <<= 1) {
    unsigned t = (threadIdx.x >= (unsigned)off) ? s[threadIdx.x - off] : 0u;
    __syncthreads();
    s[threadIdx.x] += t;
    __syncthreads();
  }
  if (i < NN) rowptr[i] = s[threadIdx.x] - v;
  if (threadIdx.x == 1023) bsum[blockIdx.x] = s[1023];
}

// C) add block offsets, zero cnt (-> fill cursor), write rowptr[NN]
__global__ __launch_bounds__(1024) void scanC_k(unsigned* __restrict__ rowptr,
                                                const unsigned* __restrict__ bsum,
                                                unsigned* __restrict__ cnt) {
  __shared__ unsigned off_s;
  if (threadIdx.x < 64) {
    unsigned v = (threadIdx.x < blockIdx.x) ? bsum[threadIdx.x] : 0u;
#pragma unroll
    for (int o = 1; o < 64; o <<= 1) v += __shfl_xor(v, o);
    if (threadIdx.x == 0) off_s = v;
  }
  __syncthreads();
  unsigned off = off_s;
  int i = blockIdx.x * 1024 + threadIdx.x;
  if (i < NN) {
    rowptr[i] += off;
    cnt[i] = 0;  // becomes fill cursor
  }
  if (blockIdx.x == SCAN_NB - 1 && threadIdx.x == 0)
    rowptr[NN] = off + bsum[SCAN_NB - 1];
}

// esrc as u16 (node ids < 65536)
__global__ void fill_k(const int* __restrict__ src, const int* __restrict__ dst,
                       const unsigned* __restrict__ rowptr, unsigned* __restrict__ cursor,
                       unsigned short* __restrict__ esrc) {
  int e = blockIdx.x * blockDim.x + threadIdx.x;
  if (e >= NE) return;
  unsigned d = (unsigned)dst[e];
  if (d >= (unsigned)NN) return;
  unsigned pos = atomicAdd(&cursor[d], 1u);
  esrc[rowptr[d] + pos] = (unsigned short)src[e];
}

// ---------------- gathers (bf16 payload, fp32 accumulate) ----------------
__global__ __launch_bounds__(256) void gather_mean_k(
    const unsigned short* __restrict__ esrc, const unsigned* __restrict__ rowptr,
    const float* __restrict__ inv, const unsigned* __restrict__ xb,
    unsigned* __restrict__ meanb) {
  int node = blockIdx.x * 4 + (threadIdx.x >> 6);
  if (node >= NN) return;
  int lane = threadIdx.x & 63;
  unsigned beg = rowptr[node], end = rowptr[node + 1];
  float ax = 0.f, ay = 0.f;
  unsigned t = beg;
  for (; t + 4 <= end; t += 4) {
    unsigned s0 = esrc[t], s1 = esrc[t + 1], s2 = esrc[t + 2], s3 = esrc[t + 3];
    unsigned v0 = xb[(size_t)s0 * 64 + lane];
    unsigned v1 = xb[(size_t)s1 * 64 + lane];
    unsigned v2 = xb[(size_t)s2 * 64 + lane];
    unsigned v3 = xb[(size_t)s3 * 64 + lane];
    ax += (bflo(v0) + bflo(v1)) + (bflo(v2) + bflo(v3));
    ay += (bfhi(v0) + bfhi(v1)) + (bfhi(v2) + bfhi(v3));
  }
  for (; t < end; ++t) {
    unsigned v0 = xb[(size_t)esrc[t] * 64 + lane];
    ax += bflo(v0); ay += bfhi(v0);
  }
  float sc = inv[node];
  meanb[(size_t)node * 64 + lane] =
      (unsigned)f2bf(ax * sc) | ((unsigned)f2bf(ay * sc) << 16);
}

__global__ __launch_bounds__(256) void gather_add_k(
    const unsigned short* __restrict__ esrc, const unsigned* __restrict__ rowptr,
    const float* __restrict__ inv, const unsigned* __restrict__ P,
    float* __restrict__ out) {
  int node = blockIdx.x * 4 + (threadIdx.x >> 6);
  if (node >= NN) return;
  int lane = threadIdx.x & 63;
  unsigned beg = rowptr[node], end = rowptr[node + 1];
  float ax = 0.f, ay = 0.f;
  unsigned t = beg;
  for (; t + 4 <= end; t += 4) {
    unsigned s0 = esrc[t], s1 = esrc[t + 1], s2 = esrc[t + 2], s3 = esrc[t + 3];
    unsigned v0 = P[(size_t)s0 * 64 + lane];
    unsigned v1 = P[(size_t)s1 * 64 + lane];
    unsigned v2 = P[(size_t)s2 * 64 + lane];
    unsigned v3 = P[(size_t)s3 * 64 + lane];
    ax += (bflo(v0) + bflo(v1)) + (bflo(v2) + bflo(v3));
    ay += (bfhi(v0) + bfhi(v1)) + (bfhi(v2) + bfhi(v3));
  }
  for (; t < end; ++t) {
    unsigned v0 = P[(size_t)esrc[t] * 64 + lane];
    ax += bflo(v0); ay += bfhi(v0);
  }
  float sc = inv[node];
  float2* O = (float2*)out;
  float2 o = O[(size_t)node * 64 + lane];
  o.x += ax * sc;
  o.y += ay * sc;
  O[(size_t)node * 64 + lane] = o;
}

// ---------------- MFMA GEMMs: 128x128 tile, 4 waves x 64x64, BK=64 (LDS, r6-proven) ----------------
// LDS: [128 rows][64 bf16], 128B rows, byte_in_row = (chunk*16) ^ ((row&7)<<4),
// identical on write and read.
#define BM 128
#define BN 128
#define BK 64

__global__ __launch_bounds__(256) void mgemm1_k(
    const unsigned short* __restrict__ xb, const unsigned short* __restrict__ meanb,
    const unsigned short* __restrict__ W1t, const float* __restrict__ b1,
    const unsigned char* __restrict__ msk, unsigned short* __restrict__ h) {
  __shared__ __align__(16) char As[BM * BK * 2];
  __shared__ __align__(16) char Bs[BN * BK * 2];
  const int tid = threadIdx.x;
  const int lane = tid & 63, wid = tid >> 6;
  const int wm = (wid >> 1) * 64, wn = (wid & 1) * 64;
  const int r16 = lane & 15, g = lane >> 4;
  const int m0 = blockIdx.x * BM;
  const int j0 = blockIdx.y * BN;

  f32x4 acc[4][4] = {};

  for (int k0 = 0; k0 < 256; k0 += BK) {
    const unsigned short* Ag = (k0 < 128) ? (xb + k0) : (meanb + (k0 - 128));
#pragma unroll
    for (int p = 0; p < 4; ++p) {
      int id = p * 256 + tid;
      int r = id >> 3, cb = id & 7;
      int grow = m0 + r;
      short8 v = {};
      if (grow < NN) v = *(const short8*)(Ag + (size_t)grow * 128 + cb * 8);
      *(short8*)(As + r * 128 + ((cb * 16) ^ ((r & 7) << 4))) = v;
    }
#pragma unroll
    for (int p = 0; p < 4; ++p) {
      int id = p * 256 + tid;
      int r = id >> 3, cb = id & 7;
      short8 v = *(const short8*)(W1t + (size_t)(j0 + r) * 256 + k0 + cb * 8);
      *(short8*)(Bs + r * 128 + ((cb * 16) ^ ((r & 7) << 4))) = v;
    }
    __syncthreads();
#pragma unroll
    for (int ks = 0; ks < 2; ++ks) {
      short8 af[4], bf[4];
#pragma unroll
      for (int f = 0; f < 4; ++f) {
        int ar = wm + f * 16 + r16;
        af[f] = *(const short8*)(As + ar * 128 + ((ks * 64 + g * 16) ^ ((ar & 7) << 4)));
        int br = wn + f * 16 + r16;
        bf[f] = *(const short8*)(Bs + br * 128 + ((ks * 64 + g * 16) ^ ((br & 7) << 4)));
      }
#pragma unroll
      for (int i = 0; i < 4; ++i)
#pragma unroll
        for (int j = 0; j < 4; ++j)
          acc[i][j] = __builtin_amdgcn_mfma_f32_16x16x32_bf16(af[i], bf[j], acc[i][j], 0, 0, 0);
    }
    __syncthreads();
  }

#pragma unroll
  for (int i = 0; i < 4; ++i)
#pragma unroll
    for (int j = 0; j < 4; ++j) {
      int col = j0 + wn + j * 16 + r16;
      float bias = b1[col];
#pragma unroll
      for (int q = 0; q < 4; ++q) {
        int row = m0 + wm + i * 16 + g * 4 + q;
        if (row < NN) {
          unsigned flat = (unsigned)row * 256u + (unsigned)col;
          float v = fmaxf(acc[i][j][q] + bias, 0.f);
          v = msk[flat] ? v * (1.0f / 0.9f) : 0.f;
          h[flat] = f2bf(v);
        }
      }
    }
}

__global__ __launch_bounds__(256) void mgemm2_k(
    const unsigned short* __restrict__ h, const unsigned short* __restrict__ W2t,
    const float* __restrict__ b2, unsigned short* __restrict__ P,
    float* __restrict__ out) {
  __shared__ __align__(16) char As[BM * BK * 2];
  __shared__ __align__(16) char Bs[BN * BK * 2];
  const int tid = threadIdx.x;
  const int lane = tid & 63, wid = tid >> 6;
  const int wm = (wid >> 1) * 64, wn = (wid & 1) * 64;
  const int r16 = lane & 15, g = lane >> 4;
  const int m0 = blockIdx.x * BM;
  const int j0 = blockIdx.y * BN;

  f32x4 acc[4][4] = {};

  for (int k0 = 0; k0 < 256; k0 += BK) {
#pragma unroll
    for (int p = 0; p < 4; ++p) {
      int id = p * 256 + tid;
      int r = id >> 3, cb = id & 7;
      int grow = m0 + r;
      short8 v = {};
      if (grow < NN) v = *(const short8*)(h + (size_t)grow * 256 + k0 + cb * 8);
      *(short8*)(As + r * 128 + ((cb * 16) ^ ((r & 7) << 4))) = v;
    }
#pragma unroll
    for (int p = 0; p < 4; ++p) {
      int id = p * 256 + tid;
      int r = id >> 3, cb = id & 7;
      short8 v = *(const short8*)(W2t + (size_t)(j0 + r) * 256 + k0 + cb * 8);
      *(short8*)(Bs + r * 128 + ((cb * 16) ^ ((r & 7) << 4))) = v;
    }
    __syncthreads();
#pragma unroll
    for (int ks = 0; ks < 2; ++ks) {
      short8 af[4], bf[4];
#pragma unroll
      for (int f = 0; f < 4; ++f) {
        int ar = wm + f * 16 + r16;
        af[f] = *(const short8*)(As + ar * 128 + ((ks * 64 + g * 16) ^ ((ar & 7) << 4)));
        int br = wn + f * 16 + r16;
        bf[f] = *(const short8*)(Bs + br * 128 + ((ks * 64 + g * 16) ^ ((br & 7) << 4)));
      }
#pragma unroll
      for (int i = 0; i < 4; ++i)
#pragma unroll
        for (int j = 0; j < 4; ++j)
          acc[i][j] = __builtin_amdgcn_mfma_f32_16x16x32_bf16(af[i], bf[j], acc[i][j], 0, 0, 0);
    }
    __syncthreads();
  }

#pragma unroll
  for (int i = 0; i < 4; ++i)
#pragma unroll
    for (int j = 0; j < 4; ++j) {
      int col = wn + j * 16 + r16;  // 0..127 within this j-half
#pragma unroll
      for (int q = 0; q < 4; ++q) {
        int row = m0 + wm + i * 16 + g * 4 + q;
        if (row < NN) {
          if (j0 == 0) {
            P[(size_t)row * 128 + col] = f2bf(acc[i][j][q]);
          } else {
            out[(size_t)row * 128 + col] = acc[i][j][q] + b2[col];
          }
        }
      }
    }
}

// ---------------- launch ----------------
extern "C" void kernel_launch(void* const* d_in, const int* in_sizes, int n_in,
                              void* d_out, int out_size, void* d_ws, size_t ws_size,
                              hipStream_t stream) {
  const float* x   = (const float*)d_in[0];
  const int*   ei  = (const int*)d_in[1];
  const float* Wl1 = (const float*)d_in[2];
  const float* Wr1 = (const float*)d_in[3];
  const float* b1  = (const float*)d_in[4];
  const float* Wl2 = (const float*)d_in[5];
  const float* Wr2 = (const float*)d_in[6];
  const float* b2  = (const float*)d_in[7];
  float* out = (float*)d_out;

  const int* src = ei;
  const int* dst = ei + NE;

  // workspace layout — NO OVERLAPS except msk/P (disjoint lifetimes), peak ~71.5 MB:
  char* ws = (char*)d_ws;
  unsigned*       rowptr = (unsigned*)ws;                      // 0x0       + 200,004
  float*          inv    = (float*)(ws + 0x40000);             // 0x40000   + 200,000
  unsigned*       cnt    = (unsigned*)(ws + 0x80000);          // 0x80000   + 200,000
  unsigned*       bsum   = (unsigned*)(ws + 0xB8000);          // 0xB8000   + 196
  unsigned short* esrc   = (unsigned short*)(ws + 0xC0000);    // 0xC0000   + 1.6MB -> 0x247000
  unsigned short* W1t    = (unsigned short*)(ws + 0x400000);   // 0x400000  + 0x20000
  unsigned short* W2t    = (unsigned short*)(ws + 0x420000);   // 0x420000  + 0x20000
  unsigned short* xb     = (unsigned short*)(ws + 0x500000);   // 0x500000  + 0xC35000
  unsigned short* meanb  = (unsigned short*)(ws + 0x1200000);  // 0x1200000 + 0xC35000
  unsigned short* h      = (unsigned short*)(ws + 0x1F00000);  // 0x1F00000 + 0x186A000
  unsigned short* P      = (unsigned short*)(ws + 0x3800000);  // 0x3800000 + 0xC35000
  unsigned char*  msk    = (unsigned char*)(ws + 0x3800000);   // aliases P: mask consumed by mgemm1 before P written

  const int TPB = 256;

  // dropout mask first (no deps), full-occupancy threefry
  mask_k<<<(NN * 256 / 4 + TPB - 1) / TPB, TPB, 0, stream>>>((uchar4*)msk);

  // prep: bf16 conversions + weight packing
  cvtx_k<<<(NN * 128 / 4 + TPB - 1) / TPB, TPB, 0, stream>>>((const float4*)x, (uint2*)xb, NN * 128 / 4);
  mkw_k<<<512, TPB, 0, stream>>>(Wl1, Wr1, Wl2, Wr2, W1t, W2t);

  // CSR build
  zero4_k<<<(NN * 4 / 16 + TPB - 1) / TPB, TPB, 0, stream>>>((float4*)cnt, NN * 4 / 16);
  count_k<<<(NE + TPB - 1) / TPB, TPB, 0, stream>>>(dst, cnt);
  inv_k<<<(NN + TPB - 1) / TPB, TPB, 0, stream>>>(cnt, inv);
  scanA_k<<<SCAN_NB, 1024, 0, stream>>>(cnt, rowptr, bsum);
  scanC_k<<<SCAN_NB, 1024, 0, stream>>>(rowptr, bsum, cnt);
  fill_k<<<(NE + TPB - 1) / TPB, TPB, 0, stream>>>(src, dst, rowptr, cnt, esrc);

  // layer 1
  gather_mean_k<<<(NN + 3) / 4, TPB, 0, stream>>>(esrc, rowptr, inv, (const unsigned*)xb, (unsigned*)meanb);
  dim3 g1((NN + BM - 1) / BM, 256 / BN);
  mgemm1_k<<<g1, TPB, 0, stream>>>(xb, meanb, W1t, b1, msk, h);

  // layer 2
  mgemm2_k<<<g1, TPB, 0, stream>>>(h, W2t, b2, P, out);
  gather_add_k<<<(NN + 3) / 4, TPB, 0, stream>>>(esrc, rowptr, inv, (const unsigned*)P, out);
}

// Round 9
// 238.512 us; speedup vs baseline: 1.1660x; 1.1660x over previous
//
#include <hip/hip_runtime.h>

#define NN 50000
#define NE 800000

typedef __attribute__((ext_vector_type(8))) short short8;
typedef __attribute__((ext_vector_type(4))) float f32x4;

#define SCAN_NB ((NN + 1023) / 1024)  // 49 blocks

// ---------------- bf16 helpers (RNE) ----------------
__device__ __forceinline__ unsigned short f2bf(float f) {
  union { float f; unsigned u; } v; v.f = f;
  unsigned r = (v.u + 0x7FFFu + ((v.u >> 16) & 1u)) >> 16;
  return (unsigned short)r;
}
__device__ __forceinline__ float bflo(unsigned u) {
  union { unsigned x; float f; } v; v.x = u << 16; return v.f;
}
__device__ __forceinline__ float bfhi(unsigned u) {
  union { unsigned x; float f; } v; v.x = u & 0xFFFF0000u; return v.f;
}

// ---------------- threefry2x32, JAX partitionable, key = (0, 42) ----------------
__device__ __forceinline__ unsigned tf_rotl(unsigned x, int r) {
#if __has_builtin(__builtin_amdgcn_alignbit)
  return __builtin_amdgcn_alignbit(x, x, 32 - r);
#else
  return (x << r) | (x >> (32 - r));
#endif
}
__device__ __forceinline__ void threefry_0_42(unsigned x0, unsigned x1,
                                              unsigned& o0, unsigned& o1) {
  const unsigned k0 = 0u, k1 = 42u;
  const unsigned k2 = k0 ^ k1 ^ 0x1BD11BDAu;
  x0 += k0; x1 += k1;
#define TF_R(r) { x0 += x1; x1 = tf_rotl(x1, (r)); x1 ^= x0; }
  TF_R(13) TF_R(15) TF_R(26) TF_R(6)
  x0 += k1; x1 += k2 + 1u;
  TF_R(17) TF_R(29) TF_R(16) TF_R(24)
  x0 += k2; x1 += k0 + 2u;
  TF_R(13) TF_R(15) TF_R(26) TF_R(6)
  x0 += k0; x1 += k1 + 3u;
  TF_R(17) TF_R(29) TF_R(16) TF_R(24)
  x0 += k1; x1 += k2 + 4u;
  TF_R(13) TF_R(15) TF_R(26) TF_R(6)
  x0 += k2; x1 += k0 + 5u;
#undef TF_R
  o0 = x0; o1 = x1;
}
__device__ __forceinline__ float dropout_scale(unsigned flat) {
  unsigned o0, o1;
  threefry_0_42(0u, flat, o0, o1);
  unsigned bits = o0 ^ o1;
  float u = __uint_as_float((bits >> 9) | 0x3f800000u) - 1.0f;
  return (u < 0.9f) ? (1.0f / 0.9f) : 0.0f;
}

// ---------------- prep: conversions / weight packing ----------------
__global__ void cvtx_k(const float4* __restrict__ x, uint2* __restrict__ xb, int n4) {
  int i = blockIdx.x * 256 + threadIdx.x;
  if (i >= n4) return;
  float4 v = x[i];
  uint2 o;
  o.x = (unsigned)f2bf(v.x) | ((unsigned)f2bf(v.y) << 16);
  o.y = (unsigned)f2bf(v.z) | ((unsigned)f2bf(v.w) << 16);
  xb[i] = o;
}

// combined weight packer: idx<65536 -> W1t, else W2t
// W1t[n][k]: k<128 -> Wr1[k][n], else Wl1[k-128][n]
// W2t[n][k]: n<128 -> Wl2[k][n], else Wr2[k][n-128]
__global__ void mkw_k(const float* __restrict__ Wl1, const float* __restrict__ Wr1,
                      const float* __restrict__ Wl2, const float* __restrict__ Wr2,
                      unsigned short* __restrict__ W1t, unsigned short* __restrict__ W2t) {
  int gid = blockIdx.x * 256 + threadIdx.x;  // 131072
  int idx = gid & 65535;
  int n = idx >> 8, k = idx & 255;
  if (gid < 65536) {
    float v = (k < 128) ? Wr1[(size_t)k * 256 + n] : Wl1[(size_t)(k - 128) * 256 + n];
    W1t[idx] = f2bf(v);
  } else {
    float v = (n < 128) ? Wl2[(size_t)k * 128 + n] : Wr2[(size_t)k * 128 + (n - 128)];
    W2t[idx] = f2bf(v);
  }
}

// ---------------- CSR build ----------------
__global__ void zero4_k(float4* p, int n4) {
  int i = blockIdx.x * blockDim.x + threadIdx.x;
  if (i < n4) p[i] = make_float4(0.f, 0.f, 0.f, 0.f);
}

__global__ void count_k(const int* __restrict__ dst, unsigned* __restrict__ cnt) {
  int e = blockIdx.x * blockDim.x + threadIdx.x;
  if (e < NE) {
    unsigned d = (unsigned)dst[e];
    if (d < (unsigned)NN) atomicAdd(&cnt[d], 1u);
  }
}

__global__ void inv_k(const unsigned* __restrict__ cnt, float* __restrict__ inv) {
  int n = blockIdx.x * blockDim.x + threadIdx.x;
  if (n < NN) inv[n] = 1.0f / fmaxf((float)cnt[n], 1.0f);
}

// two-level scan: A) block-local exclusive scan + block sums
__global__ __launch_bounds__(1024) void scanA_k(const unsigned* __restrict__ cnt,
                                                unsigned* __restrict__ rowptr,
                                                unsigned* __restrict__ bsum) {
  __shared__ unsigned s[1024];
  int i = blockIdx.x * 1024 + threadIdx.x;
  unsigned v = (i < NN) ? cnt[i] : 0u;
  s[threadIdx.x] = v;
  __syncthreads();
  for (int off = 1; off < 1024; off <<= 1) {
    unsigned t = (threadIdx.x >= (unsigned)off) ? s[threadIdx.x - off] : 0u;
    __syncthreads();
    s[threadIdx.x] += t;
    __syncthreads();
  }
  if (i < NN) rowptr[i] = s[threadIdx.x] - v;
  if (threadIdx.x == 1023) bsum[blockIdx.x] = s[1023];
}

// C) add block offsets, zero cnt (-> fill cursor), write rowptr[NN]
__global__ __launch_bounds__(1024) void scanC_k(unsigned* __restrict__ rowptr,
                                                const unsigned* __restrict__ bsum,
                                                unsigned* __restrict__ cnt) {
  __shared__ unsigned off_s;
  if (threadIdx.x < 64) {
    unsigned v = (threadIdx.x < blockIdx.x) ? bsum[threadIdx.x] : 0u;
#pragma unroll
    for (int o = 1; o < 64; o <<= 1) v += __shfl_xor(v, o);
    if (threadIdx.x == 0) off_s = v;
  }
  __syncthreads();
  unsigned off = off_s;
  int i = blockIdx.x * 1024 + threadIdx.x;
  if (i < NN) {
    rowptr[i] += off;
    cnt[i] = 0;  // becomes fill cursor
  }
  if (blockIdx.x == SCAN_NB - 1 && threadIdx.x == 0)
    rowptr[NN] = off + bsum[SCAN_NB - 1];
}

// esrc as u16 (node ids < 65536)
__global__ void fill_k(const int* __restrict__ src, const int* __restrict__ dst,
                       const unsigned* __restrict__ rowptr, unsigned* __restrict__ cursor,
                       unsigned short* __restrict__ esrc) {
  int e = blockIdx.x * blockDim.x + threadIdx.x;
  if (e >= NE) return;
  unsigned d = (unsigned)dst[e];
  if (d >= (unsigned)NN) return;
  unsigned pos = atomicAdd(&cursor[d], 1u);
  esrc[rowptr[d] + pos] = (unsigned short)src[e];
}

// ---------------- gathers (bf16 payload, fp32 accumulate) ----------------
__global__ __launch_bounds__(256) void gather_mean_k(
    const unsigned short* __restrict__ esrc, const unsigned* __restrict__ rowptr,
    const float* __restrict__ inv, const unsigned* __restrict__ xb,
    unsigned* __restrict__ meanb) {
  int node = blockIdx.x * 4 + (threadIdx.x >> 6);
  if (node >= NN) return;
  int lane = threadIdx.x & 63;
  unsigned beg = rowptr[node], end = rowptr[node + 1];
  float ax = 0.f, ay = 0.f;
  unsigned t = beg;
  for (; t + 4 <= end; t += 4) {
    unsigned s0 = esrc[t], s1 = esrc[t + 1], s2 = esrc[t + 2], s3 = esrc[t + 3];
    unsigned v0 = xb[(size_t)s0 * 64 + lane];
    unsigned v1 = xb[(size_t)s1 * 64 + lane];
    unsigned v2 = xb[(size_t)s2 * 64 + lane];
    unsigned v3 = xb[(size_t)s3 * 64 + lane];
    ax += (bflo(v0) + bflo(v1)) + (bflo(v2) + bflo(v3));
    ay += (bfhi(v0) + bfhi(v1)) + (bfhi(v2) + bfhi(v3));
  }
  for (; t < end; ++t) {
    unsigned v0 = xb[(size_t)esrc[t] * 64 + lane];
    ax += bflo(v0); ay += bfhi(v0);
  }
  float sc = inv[node];
  meanb[(size_t)node * 64 + lane] =
      (unsigned)f2bf(ax * sc) | ((unsigned)f2bf(ay * sc) << 16);
}

__global__ __launch_bounds__(256) void gather_add_k(
    const unsigned short* __restrict__ esrc, const unsigned* __restrict__ rowptr,
    const float* __restrict__ inv, const unsigned* __restrict__ P,
    float* __restrict__ out) {
  int node = blockIdx.x * 4 + (threadIdx.x >> 6);
  if (node >= NN) return;
  int lane = threadIdx.x & 63;
  unsigned beg = rowptr[node], end = rowptr[node + 1];
  float ax = 0.f, ay = 0.f;
  unsigned t = beg;
  for (; t + 4 <= end; t += 4) {
    unsigned s0 = esrc[t], s1 = esrc[t + 1], s2 = esrc[t + 2], s3 = esrc[t + 3];
    unsigned v0 = P[(size_t)s0 * 64 + lane];
    unsigned v1 = P[(size_t)s1 * 64 + lane];
    unsigned v2 = P[(size_t)s2 * 64 + lane];
    unsigned v3 = P[(size_t)s3 * 64 + lane];
    ax += (bflo(v0) + bflo(v1)) + (bflo(v2) + bflo(v3));
    ay += (bfhi(v0) + bfhi(v1)) + (bfhi(v2) + bfhi(v3));
  }
  for (; t < end; ++t) {
    unsigned v0 = P[(size_t)esrc[t] * 64 + lane];
    ax += bflo(v0); ay += bfhi(v0);
  }
  float sc = inv[node];
  float2* O = (float2*)out;
  float2 o = O[(size_t)node * 64 + lane];
  o.x += ax * sc;
  o.y += ay * sc;
  O[(size_t)node * 64 + lane] = o;
}

// ---------------- MFMA GEMMs: 64x64 block tile, 4 waves x 32x32, BK=64 ----------------
// Grid is 4x larger than the 128x128 version -> ~8 blocks/CU co-resident
// (thread-capped), hiding staging latency with TLP. LDS 16KB/block.
// LDS rows: [64 rows][64 bf16] = 128B rows, byte_in_row = (chunk*16) ^ ((row&7)<<4),
// identical on write and read.
#define BK 64

__global__ __launch_bounds__(256) void mgemm1_k(
    const unsigned short* __restrict__ xb, const unsigned short* __restrict__ meanb,
    const unsigned short* __restrict__ W1t, const float* __restrict__ b1,
    unsigned short* __restrict__ h) {
  __shared__ __align__(16) char As[64 * BK * 2];
  __shared__ __align__(16) char Bs[64 * BK * 2];
  const int tid = threadIdx.x;
  const int lane = tid & 63, wid = tid >> 6;
  const int wm = (wid >> 1) * 32, wn = (wid & 1) * 32;
  const int r16 = lane & 15, g = lane >> 4;
  const int m0 = blockIdx.x * 64;
  const int j0 = blockIdx.y * 64;

  f32x4 acc[2][2] = {};

  for (int k0 = 0; k0 < 256; k0 += BK) {
    const unsigned short* Ag = (k0 < 128) ? (xb + k0) : (meanb + (k0 - 128));
#pragma unroll
    for (int p = 0; p < 2; ++p) {
      int id = p * 256 + tid;           // 512 ids: 64 rows x 8 chunks
      int r = id >> 3, cb = id & 7;
      int grow = m0 + r;
      short8 v = {};
      if (grow < NN) v = *(const short8*)(Ag + (size_t)grow * 128 + cb * 8);
      *(short8*)(As + r * 128 + ((cb * 16) ^ ((r & 7) << 4))) = v;
    }
#pragma unroll
    for (int p = 0; p < 2; ++p) {
      int id = p * 256 + tid;
      int r = id >> 3, cb = id & 7;
      short8 v = *(const short8*)(W1t + (size_t)(j0 + r) * 256 + k0 + cb * 8);
      *(short8*)(Bs + r * 128 + ((cb * 16) ^ ((r & 7) << 4))) = v;
    }
    __syncthreads();
#pragma unroll
    for (int ks = 0; ks < 2; ++ks) {
      short8 af[2], bf[2];
#pragma unroll
      for (int f = 0; f < 2; ++f) {
        int ar = wm + f * 16 + r16;
        af[f] = *(const short8*)(As + ar * 128 + ((ks * 64 + g * 16) ^ ((ar & 7) << 4)));
        int br = wn + f * 16 + r16;
        bf[f] = *(const short8*)(Bs + br * 128 + ((ks * 64 + g * 16) ^ ((br & 7) << 4)));
      }
#pragma unroll
      for (int i = 0; i < 2; ++i)
#pragma unroll
        for (int j = 0; j < 2; ++j)
          acc[i][j] = __builtin_amdgcn_mfma_f32_16x16x32_bf16(af[i], bf[j], acc[i][j], 0, 0, 0);
    }
    __syncthreads();
  }

#pragma unroll
  for (int i = 0; i < 2; ++i)
#pragma unroll
    for (int j = 0; j < 2; ++j) {
      int col = j0 + wn + j * 16 + r16;
      float bias = b1[col];
#pragma unroll
      for (int q = 0; q < 4; ++q) {
        int row = m0 + wm + i * 16 + g * 4 + q;
        if (row < NN) {
          unsigned flat = (unsigned)row * 256u + (unsigned)col;
          float v = fmaxf(acc[i][j][q] + bias, 0.f);
          v *= dropout_scale(flat);
          h[flat] = f2bf(v);
        }
      }
    }
}

__global__ __launch_bounds__(256) void mgemm2_k(
    const unsigned short* __restrict__ h, const unsigned short* __restrict__ W2t,
    const float* __restrict__ b2, unsigned short* __restrict__ P,
    float* __restrict__ out) {
  __shared__ __align__(16) char As[64 * BK * 2];
  __shared__ __align__(16) char Bs[64 * BK * 2];
  const int tid = threadIdx.x;
  const int lane = tid & 63, wid = tid >> 6;
  const int wm = (wid >> 1) * 32, wn = (wid & 1) * 32;
  const int r16 = lane & 15, g = lane >> 4;
  const int m0 = blockIdx.x * 64;
  const int j0 = blockIdx.y * 64;

  f32x4 acc[2][2] = {};

  for (int k0 = 0; k0 < 256; k0 += BK) {
#pragma unroll
    for (int p = 0; p < 2; ++p) {
      int id = p * 256 + tid;
      int r = id >> 3, cb = id & 7;
      int grow = m0 + r;
      short8 v = {};
      if (grow < NN) v = *(const short8*)(h + (size_t)grow * 256 + k0 + cb * 8);
      *(short8*)(As + r * 128 + ((cb * 16) ^ ((r & 7) << 4))) = v;
    }
#pragma unroll
    for (int p = 0; p < 2; ++p) {
      int id = p * 256 + tid;
      int r = id >> 3, cb = id & 7;
      short8 v = *(const short8*)(W2t + (size_t)(j0 + r) * 256 + k0 + cb * 8);
      *(short8*)(Bs + r * 128 + ((cb * 16) ^ ((r & 7) << 4))) = v;
    }
    __syncthreads();
#pragma unroll
    for (int ks = 0; ks < 2; ++ks) {
      short8 af[2], bf[2];
#pragma unroll
      for (int f = 0; f < 2; ++f) {
        int ar = wm + f * 16 + r16;
        af[f] = *(const short8*)(As + ar * 128 + ((ks * 64 + g * 16) ^ ((ar & 7) << 4)));
        int br = wn + f * 16 + r16;
        bf[f] = *(const short8*)(Bs + br * 128 + ((ks * 64 + g * 16) ^ ((br & 7) << 4)));
      }
#pragma unroll
      for (int i = 0; i < 2; ++i)
#pragma unroll
        for (int j = 0; j < 2; ++j)
          acc[i][j] = __builtin_amdgcn_mfma_f32_16x16x32_bf16(af[i], bf[j], acc[i][j], 0, 0, 0);
    }
    __syncthreads();
  }

#pragma unroll
  for (int i = 0; i < 2; ++i)
#pragma unroll
    for (int j = 0; j < 2; ++j) {
      int col = j0 + wn + j * 16 + r16;  // global col in [0,256)
#pragma unroll
      for (int q = 0; q < 4; ++q) {
        int row = m0 + wm + i * 16 + g * 4 + q;
        if (row < NN) {
          if (col < 128) {
            P[(size_t)row * 128 + col] = f2bf(acc[i][j][q]);
          } else {
            out[(size_t)row * 128 + (col - 128)] = acc[i][j][q] + b2[col - 128];
          }
        }
      }
    }
}

// ---------------- launch ----------------
extern "C" void kernel_launch(void* const* d_in, const int* in_sizes, int n_in,
                              void* d_out, int out_size, void* d_ws, size_t ws_size,
                              hipStream_t stream) {
  const float* x   = (const float*)d_in[0];
  const int*   ei  = (const int*)d_in[1];
  const float* Wl1 = (const float*)d_in[2];
  const float* Wr1 = (const float*)d_in[3];
  const float* b1  = (const float*)d_in[4];
  const float* Wl2 = (const float*)d_in[5];
  const float* Wr2 = (const float*)d_in[6];
  const float* b2  = (const float*)d_in[7];
  float* out = (float*)d_out;

  const int* src = ei;
  const int* dst = ei + NE;

  // workspace layout — NO OVERLAPS, peak ~71.5 MB:
  char* ws = (char*)d_ws;
  unsigned*       rowptr = (unsigned*)ws;                      // 0x0       + 200,004
  float*          inv    = (float*)(ws + 0x40000);             // 0x40000   + 200,000
  unsigned*       cnt    = (unsigned*)(ws + 0x80000);          // 0x80000   + 200,000
  unsigned*       bsum   = (unsigned*)(ws + 0xB8000);          // 0xB8000   + 196
  unsigned short* esrc   = (unsigned short*)(ws + 0xC0000);    // 0xC0000   + 1.6MB
  unsigned short* W1t    = (unsigned short*)(ws + 0x400000);   // 0x400000  + 0x20000
  unsigned short* W2t    = (unsigned short*)(ws + 0x420000);   // 0x420000  + 0x20000
  unsigned short* xb     = (unsigned short*)(ws + 0x500000);   // 0x500000  + 0xC35000
  unsigned short* meanb  = (unsigned short*)(ws + 0x1200000);  // 0x1200000 + 0xC35000
  unsigned short* h      = (unsigned short*)(ws + 0x1F00000);  // 0x1F00000 + 0x186A000
  unsigned short* P      = (unsigned short*)(ws + 0x3800000);  // 0x3800000 + 0xC35000

  const int TPB = 256;

  // prep: bf16 conversions + weight packing
  cvtx_k<<<(NN * 128 / 4 + TPB - 1) / TPB, TPB, 0, stream>>>((const float4*)x, (uint2*)xb, NN * 128 / 4);
  mkw_k<<<512, TPB, 0, stream>>>(Wl1, Wr1, Wl2, Wr2, W1t, W2t);

  // CSR build
  zero4_k<<<(NN * 4 / 16 + TPB - 1) / TPB, TPB, 0, stream>>>((float4*)cnt, NN * 4 / 16);
  count_k<<<(NE + TPB - 1) / TPB, TPB, 0, stream>>>(dst, cnt);
  inv_k<<<(NN + TPB - 1) / TPB, TPB, 0, stream>>>(cnt, inv);
  scanA_k<<<SCAN_NB, 1024, 0, stream>>>(cnt, rowptr, bsum);
  scanC_k<<<SCAN_NB, 1024, 0, stream>>>(rowptr, bsum, cnt);
  fill_k<<<(NE + TPB - 1) / TPB, TPB, 0, stream>>>(src, dst, rowptr, cnt, esrc);

  // layer 1
  gather_mean_k<<<(NN + 3) / 4, TPB, 0, stream>>>(esrc, rowptr, inv, (const unsigned*)xb, (unsigned*)meanb);
  dim3 g1((NN + 63) / 64, 4);
  mgemm1_k<<<g1, TPB, 0, stream>>>(xb, meanb, W1t, b1, h);

  // layer 2
  mgemm2_k<<<g1, TPB, 0, stream>>>(h, W2t, b2, P, out);
  gather_add_k<<<(NN + 3) / 4, TPB, 0, stream>>>(esrc, rowptr, inv, (const unsigned*)P, out);
}

// Round 10
// 233.722 us; speedup vs baseline: 1.1899x; 1.0205x over previous
//
#include <hip/hip_runtime.h>

#define NN 50000
#define NE 800000

typedef __attribute__((ext_vector_type(8))) short short8;
typedef __attribute__((ext_vector_type(4))) float f32x4;

#define SCAN_NB ((NN + 1023) / 1024)  // 49 blocks

// global -> LDS direct DMA, 16B per lane; LDS dest = wave-uniform base + lane*16
#define GLDS(g, l)                                                              \
  __builtin_amdgcn_global_load_lds(                                             \
      (const __attribute__((address_space(1))) void*)(g),                       \
      (__attribute__((address_space(3))) void*)(l), 16, 0, 0)

// ---------------- bf16 helpers (RNE) ----------------
__device__ __forceinline__ unsigned short f2bf(float f) {
  union { float f; unsigned u; } v; v.f = f;
  unsigned r = (v.u + 0x7FFFu + ((v.u >> 16) & 1u)) >> 16;
  return (unsigned short)r;
}
__device__ __forceinline__ float bflo(unsigned u) {
  union { unsigned x; float f; } v; v.x = u << 16; return v.f;
}
__device__ __forceinline__ float bfhi(unsigned u) {
  union { unsigned x; float f; } v; v.x = u & 0xFFFF0000u; return v.f;
}

// ---------------- threefry2x32, JAX partitionable, key = (0, 42) ----------------
__device__ __forceinline__ unsigned tf_rotl(unsigned x, int r) {
#if __has_builtin(__builtin_amdgcn_alignbit)
  return __builtin_amdgcn_alignbit(x, x, 32 - r);
#else
  return (x << r) | (x >> (32 - r));
#endif
}
__device__ __forceinline__ void threefry_0_42(unsigned x0, unsigned x1,
                                              unsigned& o0, unsigned& o1) {
  const unsigned k0 = 0u, k1 = 42u;
  const unsigned k2 = k0 ^ k1 ^ 0x1BD11BDAu;
  x0 += k0; x1 += k1;
#define TF_R(r) { x0 += x1; x1 = tf_rotl(x1, (r)); x1 ^= x0; }
  TF_R(13) TF_R(15) TF_R(26) TF_R(6)
  x0 += k1; x1 += k2 + 1u;
  TF_R(17) TF_R(29) TF_R(16) TF_R(24)
  x0 += k2; x1 += k0 + 2u;
  TF_R(13) TF_R(15) TF_R(26) TF_R(6)
  x0 += k0; x1 += k1 + 3u;
  TF_R(17) TF_R(29) TF_R(16) TF_R(24)
  x0 += k1; x1 += k2 + 4u;
  TF_R(13) TF_R(15) TF_R(26) TF_R(6)
  x0 += k2; x1 += k0 + 5u;
#undef TF_R
  o0 = x0; o1 = x1;
}
__device__ __forceinline__ float dropout_scale(unsigned flat) {
  unsigned o0, o1;
  threefry_0_42(0u, flat, o0, o1);
  unsigned bits = o0 ^ o1;
  float u = __uint_as_float((bits >> 9) | 0x3f800000u) - 1.0f;
  return (u < 0.9f) ? (1.0f / 0.9f) : 0.0f;
}

// ---------------- prep: conversions / weight packing ----------------
__global__ void cvtx_k(const float4* __restrict__ x, uint2* __restrict__ xb, int n4) {
  int i = blockIdx.x * 256 + threadIdx.x;
  if (i >= n4) return;
  float4 v = x[i];
  uint2 o;
  o.x = (unsigned)f2bf(v.x) | ((unsigned)f2bf(v.y) << 16);
  o.y = (unsigned)f2bf(v.z) | ((unsigned)f2bf(v.w) << 16);
  xb[i] = o;
}

// combined weight packer: idx<65536 -> W1t, else W2t
// W1t[n][k]: k<128 -> Wr1[k][n], else Wl1[k-128][n]
// W2t[n][k]: n<128 -> Wl2[k][n], else Wr2[k][n-128]
__global__ void mkw_k(const float* __restrict__ Wl1, const float* __restrict__ Wr1,
                      const float* __restrict__ Wl2, const float* __restrict__ Wr2,
                      unsigned short* __restrict__ W1t, unsigned short* __restrict__ W2t) {
  int gid = blockIdx.x * 256 + threadIdx.x;  // 131072
  int idx = gid & 65535;
  int n = idx >> 8, k = idx & 255;
  if (gid < 65536) {
    float v = (k < 128) ? Wr1[(size_t)k * 256 + n] : Wl1[(size_t)(k - 128) * 256 + n];
    W1t[idx] = f2bf(v);
  } else {
    float v = (n < 128) ? Wl2[(size_t)k * 128 + n] : Wr2[(size_t)k * 128 + (n - 128)];
    W2t[idx] = f2bf(v);
  }
}

// ---------------- CSR build ----------------
__global__ void zero4_k(float4* p, int n4) {
  int i = blockIdx.x * blockDim.x + threadIdx.x;
  if (i < n4) p[i] = make_float4(0.f, 0.f, 0.f, 0.f);
}

__global__ void count_k(const int* __restrict__ dst, unsigned* __restrict__ cnt) {
  int e = blockIdx.x * blockDim.x + threadIdx.x;
  if (e < NE) {
    unsigned d = (unsigned)dst[e];
    if (d < (unsigned)NN) atomicAdd(&cnt[d], 1u);
  }
}

// two-level scan: A) block-local exclusive scan + block sums
__global__ __launch_bounds__(1024) void scanA_k(const unsigned* __restrict__ cnt,
                                                unsigned* __restrict__ rowptr,
                                                unsigned* __restrict__ bsum) {
  __shared__ unsigned s[1024];
  int i = blockIdx.x * 1024 + threadIdx.x;
  unsigned v = (i < NN) ? cnt[i] : 0u;
  s[threadIdx.x] = v;
  __syncthreads();
  for (int off = 1; off < 1024; off <<= 1) {
    unsigned t = (threadIdx.x >= (unsigned)off) ? s[threadIdx.x - off] : 0u;
    __syncthreads();
    s[threadIdx.x] += t;
    __syncthreads();
  }
  if (i < NN) rowptr[i] = s[threadIdx.x] - v;
  if (threadIdx.x == 1023) bsum[blockIdx.x] = s[1023];
}

// C) add block offsets, compute inv, zero cnt (-> fill cursor), write rowptr[NN]
__global__ __launch_bounds__(1024) void scanC_k(unsigned* __restrict__ rowptr,
                                                const unsigned* __restrict__ bsum,
                                                unsigned* __restrict__ cnt,
                                                float* __restrict__ inv) {
  __shared__ unsigned off_s;
  if (threadIdx.x < 64) {
    unsigned v = (threadIdx.x < blockIdx.x) ? bsum[threadIdx.x] : 0u;
#pragma unroll
    for (int o = 1; o < 64; o <<= 1) v += __shfl_xor(v, o);
    if (threadIdx.x == 0) off_s = v;
  }
  __syncthreads();
  unsigned off = off_s;
  int i = blockIdx.x * 1024 + threadIdx.x;
  if (i < NN) {
    unsigned c = cnt[i];
    inv[i] = 1.0f / fmaxf((float)c, 1.0f);
    rowptr[i] += off;
    cnt[i] = 0;  // becomes fill cursor
  }
  if (blockIdx.x == SCAN_NB - 1 && threadIdx.x == 0)
    rowptr[NN] = off + bsum[SCAN_NB - 1];
}

// esrc as u16 (node ids < 65536)
__global__ void fill_k(const int* __restrict__ src, const int* __restrict__ dst,
                       const unsigned* __restrict__ rowptr, unsigned* __restrict__ cursor,
                       unsigned short* __restrict__ esrc) {
  int e = blockIdx.x * blockDim.x + threadIdx.x;
  if (e >= NE) return;
  unsigned d = (unsigned)dst[e];
  if (d >= (unsigned)NN) return;
  unsigned pos = atomicAdd(&cursor[d], 1u);
  esrc[rowptr[d] + pos] = (unsigned short)src[e];
}

// ---------------- gathers (bf16 payload, fp32 accumulate) ----------------
__global__ __launch_bounds__(256) void gather_mean_k(
    const unsigned short* __restrict__ esrc, const unsigned* __restrict__ rowptr,
    const float* __restrict__ inv, const unsigned* __restrict__ xb,
    unsigned* __restrict__ meanb) {
  int node = blockIdx.x * 4 + (threadIdx.x >> 6);
  if (node >= NN) return;
  int lane = threadIdx.x & 63;
  unsigned beg = rowptr[node], end = rowptr[node + 1];
  float ax = 0.f, ay = 0.f;
  unsigned t = beg;
  for (; t + 4 <= end; t += 4) {
    unsigned s0 = esrc[t], s1 = esrc[t + 1], s2 = esrc[t + 2], s3 = esrc[t + 3];
    unsigned v0 = xb[(size_t)s0 * 64 + lane];
    unsigned v1 = xb[(size_t)s1 * 64 + lane];
    unsigned v2 = xb[(size_t)s2 * 64 + lane];
    unsigned v3 = xb[(size_t)s3 * 64 + lane];
    ax += (bflo(v0) + bflo(v1)) + (bflo(v2) + bflo(v3));
    ay += (bfhi(v0) + bfhi(v1)) + (bfhi(v2) + bfhi(v3));
  }
  for (; t < end; ++t) {
    unsigned v0 = xb[(size_t)esrc[t] * 64 + lane];
    ax += bflo(v0); ay += bfhi(v0);
  }
  float sc = inv[node];
  meanb[(size_t)node * 64 + lane] =
      (unsigned)f2bf(ax * sc) | ((unsigned)f2bf(ay * sc) << 16);
}

__global__ __launch_bounds__(256) void gather_add_k(
    const unsigned short* __restrict__ esrc, const unsigned* __restrict__ rowptr,
    const float* __restrict__ inv, const unsigned* __restrict__ P,
    float* __restrict__ out) {
  int node = blockIdx.x * 4 + (threadIdx.x >> 6);
  if (node >= NN) return;
  int lane = threadIdx.x & 63;
  unsigned beg = rowptr[node], end = rowptr[node + 1];
  float ax = 0.f, ay = 0.f;
  unsigned t = beg;
  for (; t + 4 <= end; t += 4) {
    unsigned s0 = esrc[t], s1 = esrc[t + 1], s2 = esrc[t + 2], s3 = esrc[t + 3];
    unsigned v0 = P[(size_t)s0 * 64 + lane];
    unsigned v1 = P[(size_t)s1 * 64 + lane];
    unsigned v2 = P[(size_t)s2 * 64 + lane];
    unsigned v3 = P[(size_t)s3 * 64 + lane];
    ax += (bflo(v0) + bflo(v1)) + (bflo(v2) + bflo(v3));
    ay += (bfhi(v0) + bfhi(v1)) + (bfhi(v2) + bfhi(v3));
  }
  for (; t < end; ++t) {
    unsigned v0 = P[(size_t)esrc[t] * 64 + lane];
    ax += bflo(v0); ay += bfhi(v0);
  }
  float sc = inv[node];
  float2* O = (float2*)out;
  float2 o = O[(size_t)node * 64 + lane];
  o.x += ax * sc;
  o.y += ay * sc;
  O[(size_t)node * 64 + lane] = o;
}

// ---------------- MFMA GEMMs: 64x64 tile, 4 waves x 32x32, K staged via global_load_lds ----------------
// LDS slot (r, c) [c = 16B chunk 0..7] holds global chunk c ^ (r&7) of row r:
// staging writes LINEARLY (slot id = p*256+tid) from inverse-swizzled global
// source; reads XOR the byte offset. Same involution both sides.

__global__ __launch_bounds__(256) void mgemm1_k(
    const unsigned short* __restrict__ xb, const unsigned short* __restrict__ meanb,
    const unsigned short* __restrict__ W1t, const float* __restrict__ b1,
    unsigned short* __restrict__ h) {
  __shared__ __align__(16) char As[64 * 64 * 2];
  __shared__ __align__(16) char Bs[64 * 64 * 2];
  const int tid = threadIdx.x;
  const int lane = tid & 63, wid = tid >> 6;
  const int wm = (wid >> 1) * 32, wn = (wid & 1) * 32;
  const int r16 = lane & 15, g = lane >> 4;
  const int m0 = blockIdx.x * 64;
  const int j0 = blockIdx.y * 64;
  const int wbase = (tid & ~63);  // wave*64

  auto stageA = [&](int s) {
    const unsigned short* base = (s < 2) ? (xb + s * 64) : (meanb + (s - 2) * 64);
#pragma unroll
    for (int p = 0; p < 2; ++p) {
      int id = p * 256 + tid;
      int r = id >> 3, cb = id & 7;
      int grow = m0 + r;
      if (grow >= NN) grow = NN - 1;  // dead rows, masked at store
      GLDS(base + (size_t)grow * 128 + ((cb ^ (r & 7)) << 3),
           As + ((p * 256 + wbase) << 4));
    }
  };
  auto stageB = [&](int s) {
#pragma unroll
    for (int p = 0; p < 2; ++p) {
      int id = p * 256 + tid;
      int r = id >> 3, cb = id & 7;
      GLDS(W1t + (size_t)(j0 + r) * 256 + s * 64 + ((cb ^ (r & 7)) << 3),
           Bs + ((p * 256 + wbase) << 4));
    }
  };

  stageA(0); stageB(0);  // loads fly while threefry runs

  // dropout scales, fully unrolled -> static indexing, overlaps staging latency
  float dsc[2][2][4];
#pragma unroll
  for (int i = 0; i < 2; ++i)
#pragma unroll
    for (int j = 0; j < 2; ++j) {
      int col = j0 + wn + j * 16 + r16;
#pragma unroll
      for (int q = 0; q < 4; ++q) {
        int row = m0 + wm + i * 16 + g * 4 + q;
        dsc[i][j][q] = dropout_scale((unsigned)row * 256u + (unsigned)col);
      }
    }

  f32x4 acc[2][2] = {};

  for (int s = 0; s < 4; ++s) {
    __syncthreads();  // compiler drains vmcnt: staged tile ready
#pragma unroll
    for (int ks = 0; ks < 2; ++ks) {
      short8 af[2], bf[2];
#pragma unroll
      for (int f = 0; f < 2; ++f) {
        int ar = wm + f * 16 + r16;
        af[f] = *(const short8*)(As + ar * 128 + ((ks * 64 + g * 16) ^ ((ar & 7) << 4)));
        int br = wn + f * 16 + r16;
        bf[f] = *(const short8*)(Bs + br * 128 + ((ks * 64 + g * 16) ^ ((br & 7) << 4)));
      }
#pragma unroll
      for (int i = 0; i < 2; ++i)
#pragma unroll
        for (int j = 0; j < 2; ++j)
          acc[i][j] = __builtin_amdgcn_mfma_f32_16x16x32_bf16(af[i], bf[j], acc[i][j], 0, 0, 0);
    }
    if (s < 3) {
      __syncthreads();  // all waves done reading LDS
      stageA(s + 1); stageB(s + 1);
    }
  }

#pragma unroll
  for (int i = 0; i < 2; ++i)
#pragma unroll
    for (int j = 0; j < 2; ++j) {
      int col = j0 + wn + j * 16 + r16;
      float bias = b1[col];
#pragma unroll
      for (int q = 0; q < 4; ++q) {
        int row = m0 + wm + i * 16 + g * 4 + q;
        if (row < NN) {
          float v = fmaxf(acc[i][j][q] + bias, 0.f) * dsc[i][j][q];
          h[(size_t)row * 256 + col] = f2bf(v);
        }
      }
    }
}

__global__ __launch_bounds__(256) void mgemm2_k(
    const unsigned short* __restrict__ h, const unsigned short* __restrict__ W2t,
    const float* __restrict__ b2, unsigned short* __restrict__ P,
    float* __restrict__ out) {
  __shared__ __align__(16) char As[64 * 64 * 2];
  __shared__ __align__(16) char Bs[64 * 64 * 2];
  const int tid = threadIdx.x;
  const int lane = tid & 63, wid = tid >> 6;
  const int wm = (wid >> 1) * 32, wn = (wid & 1) * 32;
  const int r16 = lane & 15, g = lane >> 4;
  const int m0 = blockIdx.x * 64;
  const int j0 = blockIdx.y * 64;
  const int wbase = (tid & ~63);

  auto stageA = [&](int s) {
#pragma unroll
    for (int p = 0; p < 2; ++p) {
      int id = p * 256 + tid;
      int r = id >> 3, cb = id & 7;
      int grow = m0 + r;
      if (grow >= NN) grow = NN - 1;
      GLDS(h + (size_t)grow * 256 + s * 64 + ((cb ^ (r & 7)) << 3),
           As + ((p * 256 + wbase) << 4));
    }
  };
  auto stageB = [&](int s) {
#pragma unroll
    for (int p = 0; p < 2; ++p) {
      int id = p * 256 + tid;
      int r = id >> 3, cb = id & 7;
      GLDS(W2t + (size_t)(j0 + r) * 256 + s * 64 + ((cb ^ (r & 7)) << 3),
           Bs + ((p * 256 + wbase) << 4));
    }
  };

  stageA(0); stageB(0);

  f32x4 acc[2][2] = {};

  for (int s = 0; s < 4; ++s) {
    __syncthreads();
#pragma unroll
    for (int ks = 0; ks < 2; ++ks) {
      short8 af[2], bf[2];
#pragma unroll
      for (int f = 0; f < 2; ++f) {
        int ar = wm + f * 16 + r16;
        af[f] = *(const short8*)(As + ar * 128 + ((ks * 64 + g * 16) ^ ((ar & 7) << 4)));
        int br = wn + f * 16 + r16;
        bf[f] = *(const short8*)(Bs + br * 128 + ((ks * 64 + g * 16) ^ ((br & 7) << 4)));
      }
#pragma unroll
      for (int i = 0; i < 2; ++i)
#pragma unroll
        for (int j = 0; j < 2; ++j)
          acc[i][j] = __builtin_amdgcn_mfma_f32_16x16x32_bf16(af[i], bf[j], acc[i][j], 0, 0, 0);
    }
    if (s < 3) {
      __syncthreads();
      stageA(s + 1); stageB(s + 1);
    }
  }

#pragma unroll
  for (int i = 0; i < 2; ++i)
#pragma unroll
    for (int j = 0; j < 2; ++j) {
      int col = j0 + wn + j * 16 + r16;  // global col in [0,256)
#pragma unroll
      for (int q = 0; q < 4; ++q) {
        int row = m0 + wm + i * 16 + g * 4 + q;
        if (row < NN) {
          if (col < 128) {
            P[(size_t)row * 128 + col] = f2bf(acc[i][j][q]);
          } else {
            out[(size_t)row * 128 + (col - 128)] = acc[i][j][q] + b2[col - 128];
          }
        }
      }
    }
}

// ---------------- launch ----------------
extern "C" void kernel_launch(void* const* d_in, const int* in_sizes, int n_in,
                              void* d_out, int out_size, void* d_ws, size_t ws_size,
                              hipStream_t stream) {
  const float* x   = (const float*)d_in[0];
  const int*   ei  = (const int*)d_in[1];
  const float* Wl1 = (const float*)d_in[2];
  const float* Wr1 = (const float*)d_in[3];
  const float* b1  = (const float*)d_in[4];
  const float* Wl2 = (const float*)d_in[5];
  const float* Wr2 = (const float*)d_in[6];
  const float* b2  = (const float*)d_in[7];
  float* out = (float*)d_out;

  const int* src = ei;
  const int* dst = ei + NE;

  // workspace layout — NO OVERLAPS, peak ~71.5 MB:
  char* ws = (char*)d_ws;
  unsigned*       rowptr = (unsigned*)ws;                      // 0x0       + 200,004
  float*          inv    = (float*)(ws + 0x40000);             // 0x40000   + 200,000
  unsigned*       cnt    = (unsigned*)(ws + 0x80000);          // 0x80000   + 200,000
  unsigned*       bsum   = (unsigned*)(ws + 0xB8000);          // 0xB8000   + 196
  unsigned short* esrc   = (unsigned short*)(ws + 0xC0000);    // 0xC0000   + 1.6MB
  unsigned short* W1t    = (unsigned short*)(ws + 0x400000);   // 0x400000  + 0x20000
  unsigned short* W2t    = (unsigned short*)(ws + 0x420000);   // 0x420000  + 0x20000
  unsigned short* xb     = (unsigned short*)(ws + 0x500000);   // 0x500000  + 0xC35000
  unsigned short* meanb  = (unsigned short*)(ws + 0x1200000);  // 0x1200000 + 0xC35000
  unsigned short* h      = (unsigned short*)(ws + 0x1F00000);  // 0x1F00000 + 0x186A000
  unsigned short* P      = (unsigned short*)(ws + 0x3800000);  // 0x3800000 + 0xC35000

  const int TPB = 256;

  // prep: bf16 conversions + weight packing
  cvtx_k<<<(NN * 128 / 4 + TPB - 1) / TPB, TPB, 0, stream>>>((const float4*)x, (uint2*)xb, NN * 128 / 4);
  mkw_k<<<512, TPB, 0, stream>>>(Wl1, Wr1, Wl2, Wr2, W1t, W2t);

  // CSR build
  zero4_k<<<(NN * 4 / 16 + TPB - 1) / TPB, TPB, 0, stream>>>((float4*)cnt, NN * 4 / 16);
  count_k<<<(NE + TPB - 1) / TPB, TPB, 0, stream>>>(dst, cnt);
  scanA_k<<<SCAN_NB, 1024, 0, stream>>>(cnt, rowptr, bsum);
  scanC_k<<<SCAN_NB, 1024, 0, stream>>>(rowptr, bsum, cnt, inv);  // + inv, cnt->cursor
  fill_k<<<(NE + TPB - 1) / TPB, TPB, 0, stream>>>(src, dst, rowptr, cnt, esrc);

  // layer 1
  gather_mean_k<<<(NN + 3) / 4, TPB, 0, stream>>>(esrc, rowptr, inv, (const unsigned*)xb, (unsigned*)meanb);
  dim3 g1((NN + 63) / 64, 4);
  mgemm1_k<<<g1, TPB, 0, stream>>>(xb, meanb, W1t, b1, h);

  // layer 2
  mgemm2_k<<<g1, TPB, 0, stream>>>(h, W2t, b2, P, out);
  gather_add_k<<<(NN + 3) / 4, TPB, 0, stream>>>(esrc, rowptr, inv, (const unsigned*)P, out);
}